// Round 7
// baseline (441.513 us; speedup 1.0000x reference)
//
#include <hip/hip_runtime.h>

#define D 128
#define BROWS 32
#define BSHIFT 5
#define COLBITS 17
#define COLMASK 0x1FFFF
#define CHUNKS 256
#define CAP 1280
#define CVTB 1792
#define PBLK 1024
#define DSPLIT 8      // embedding-dim split: 8 planes of 16 dims (3.3 MB each -> L2-resident per XCD)
#define DIMW 8        // u32 words (2 bf16 dims each) per plane per node
#define RSCAP 4096    // max bucket run sorted in-place via LDS (mean 1024, sigma 32)
#define TCAP 1536     // phase-4 LDS staging chunk (12 KB)
// XCD-grouping permutation of chunk->matrix-slot (valid for CHUNKS==256)
#define PERM(c) ((((c) & 7) << 5) | ((c) >> 3))

typedef float vf4 __attribute__((ext_vector_type(4)));   // clang vector: nontemporal-store legal

// ---------- Phase 1 (fused): per-chunk bucket histogram + emb fp32->bf16 plane convert ----------
__global__ void k_prep(const int* __restrict__ rows, int E, int CE, int nb,
                       int* __restrict__ M,
                       const float2* __restrict__ emb, unsigned* __restrict__ q,
                       int n, int cvtb) {
    int histBlocks = gridDim.x - cvtb;
    if ((int)blockIdx.x >= histBlocks) {
        int stride = cvtb * PBLK;
        size_t planeWords = (size_t)(n >> 3);          // N*8 words per plane
        for (int i = ((int)blockIdx.x - histBlocks) * PBLK + threadIdx.x; i < n; i += stride) {
            float2 f = emb[i];
            unsigned lo = __float_as_uint(f.x), hi = __float_as_uint(f.y);
            lo = (lo + 0x7FFFu + ((lo >> 16) & 1u)) & 0xFFFF0000u;   // RNE to bf16
            hi = (hi + 0x7FFFu + ((hi >> 16) & 1u)) & 0xFFFF0000u;
            size_t plane = (size_t)((i >> 3) & 7);
            size_t w     = (size_t)(((i >> 6) << 3) | (i & 7));
            q[plane * planeWords + w] = hi | (lo >> 16);
        }
        return;
    }
    extern __shared__ int h[];
    int c = blockIdx.x;
    int slot = PERM(c);
    for (int i = threadIdx.x; i < nb; i += PBLK) h[i] = 0;
    __syncthreads();
    int beg = c * CE, end = min(E, beg + CE);
    for (int e = beg + threadIdx.x; e < end; e += PBLK)
        atomicAdd(&h[rows[e] >> BSHIFT], 1);            // int LDS atomic: native ds_add
    __syncthreads();
    for (int i = threadIdx.x; i < nb; i += PBLK) M[(size_t)i * CHUNKS + slot] = h[i];
}

// ---------- Phase 2: hierarchical exclusive scan ----------
__global__ void k_scan1(const int* __restrict__ M, int flat,
                        int* __restrict__ O, int* __restrict__ bs) {
    __shared__ int s[1024];
    int i = blockIdx.x * 1024 + threadIdx.x;
    int v = (i < flat) ? M[i] : 0;
    s[threadIdx.x] = v;
    __syncthreads();
    for (int off = 1; off < 1024; off <<= 1) {
        int t = (threadIdx.x >= (unsigned)off) ? s[threadIdx.x - off] : 0;
        __syncthreads();
        s[threadIdx.x] += t;
        __syncthreads();
    }
    if (i < flat) O[i] = s[threadIdx.x] - v;
    if (threadIdx.x == 1023) bs[blockIdx.x] = s[1023];
}

__global__ void k_scan2(int* __restrict__ bs, int nblk) {
    __shared__ int s[1024];
    __shared__ int carry;
    if (threadIdx.x == 0) carry = 0;
    __syncthreads();
    for (int base = 0; base < nblk; base += 1024) {
        int i = base + (int)threadIdx.x;
        int v = (i < nblk) ? bs[i] : 0;
        s[threadIdx.x] = v;
        __syncthreads();
        for (int off = 1; off < 1024; off <<= 1) {
            int t = (threadIdx.x >= (unsigned)off) ? s[threadIdx.x - off] : 0;
            __syncthreads();
            s[threadIdx.x] += t;
            __syncthreads();
        }
        int c = carry;
        if (i < nblk) bs[i] = c + s[threadIdx.x] - v;
        __syncthreads();
        if (threadIdx.x == 0) carry = c + s[1023];
        __syncthreads();
    }
}

// ---------- Phase 3: bucket-sorted scatter via LDS cursors (proven round-1) ----------
__global__ void k_mscatter(const int* __restrict__ rows, const int* __restrict__ cols,
                           const float* __restrict__ vals, int E, int CE, int nb,
                           const int* __restrict__ O, const int* __restrict__ bs,
                           unsigned long long* __restrict__ sorted) {
    extern __shared__ int cur[];
    int c = blockIdx.x;
    int slot = PERM(c);
    for (int b = threadIdx.x; b < nb; b += PBLK) {
        int f = b * CHUNKS + slot;
        cur[b] = O[f] + bs[f >> 10];
    }
    __syncthreads();
    int beg = c * CE, end = min(E, beg + CE);
    for (int e = beg + threadIdx.x; e < end; e += PBLK) {
        int r = rows[e];
        int b = r >> BSHIFT;
        int pos = atomicAdd(&cur[b], 1);
        unsigned packed = ((unsigned)(r & (BROWS - 1)) << COLBITS) | (unsigned)cols[e];
        unsigned long long rec =
            ((unsigned long long)__float_as_uint(vals[e]) << 32) | (unsigned long long)packed;
        if (pos >= 0 && pos < E)
            sorted[pos] = rec;
    }
}

// ---------- Phase 3.5: per-bucket in-place row sort + global CSR rowptr ----------
__global__ __launch_bounds__(256) void k_rowsort(unsigned long long* __restrict__ sorted,
                                                 const int* __restrict__ O,
                                                 const int* __restrict__ bs,
                                                 int* __restrict__ rowptr,
                                                 int nb, int N, int E) {
    __shared__ unsigned long long recs[RSCAP];
    __shared__ int cnt[BROWS], cur[BROWS];
    int b = blockIdx.x;
    int f0 = b * CHUNKS;
    int beg = O[f0] + bs[f0 >> 10];
    int end;
    if (b + 1 < nb) { int f1 = (b + 1) * CHUNKS; end = O[f1] + bs[f1 >> 10]; }
    else            end = E;
    beg = max(0, min(beg, E));
    end = max(beg, min(end, E));
    int run = end - beg;
    if (b == 0 && threadIdx.x == 0) rowptr[N] = E;
    if (run > RSCAP) {
        if (threadIdx.x < BROWS) {
            int row = b * BROWS + (int)threadIdx.x;
            if (row < N) rowptr[row] = -beg - 2;       // sentinel, decodes bucket start
        }
        return;
    }
    if (threadIdx.x < BROWS) cnt[threadIdx.x] = 0;
    for (int k = threadIdx.x; k < run; k += 256) recs[k] = sorted[beg + k];
    __syncthreads();
    for (int k = threadIdx.x; k < run; k += 256)
        atomicAdd(&cnt[((unsigned)recs[k] >> COLBITS) & (BROWS - 1)], 1);
    __syncthreads();
    if (threadIdx.x < BROWS) {
        int v = cnt[threadIdx.x];
        int incl = v;
#pragma unroll
        for (int off = 1; off < BROWS; off <<= 1) {
            int u = __shfl_up(incl, off);
            if ((int)threadIdx.x >= off) incl += u;
        }
        int excl = incl - v;
        cur[threadIdx.x] = excl;
        int row = b * BROWS + (int)threadIdx.x;
        if (row < N) rowptr[row] = beg + excl;
    }
    __syncthreads();
    for (int k = threadIdx.x; k < run; k += 256) {
        unsigned long long rc = recs[k];
        int row = ((unsigned)rc >> COLBITS) & (BROWS - 1);
        int pos = atomicAdd(&cur[row], 1);
        if (pos >= 0 && pos < run) sorted[beg + pos] = rc;
    }
}

// ---------- Phase 4: dim-sliced row-run streaming, 16-edge x uint2 lanes ----------
// Block (bucket b, plane r=blockIdx&7) computes out[b*32..+32)[16r..16r+16).
// Lane layout: e16 = lane>>2 (16 edges in flight per wave-instr), dp = lane&3
// (one uint2 = 4 bf16 dims). Halves wave-instruction count vs the 8-edge x u32
// layout (VALUBusy was 73% -> VALU-issue-bound).
__global__ __launch_bounds__(256) void k_dimtile(const unsigned long long* __restrict__ sorted,
                                                 const int* __restrict__ rowptr,
                                                 const unsigned* __restrict__ q,
                                                 float* __restrict__ out,
                                                 int N, int E) {
    __shared__ unsigned long long recs[TCAP];
    __shared__ int rp[BROWS + 1];
    int r = blockIdx.x & (DSPLIT - 1);
    int b = blockIdx.x >> 3;
    if (threadIdx.x <= BROWS) {
        int row = b * BROWS + (int)threadIdx.x;
        rp[threadIdx.x] = (row <= N) ? rowptr[row] : E;
    }
    __syncthreads();
    int rp0 = rp[0];
    bool srt = rp0 >= 0;                               // sorted bucket?
    int beg = srt ? rp0 : (-rp0 - 2);
    int endv = rp[BROWS];
    int end = (endv >= 0) ? endv : (-endv - 2);
    beg = max(0, min(beg, E));
    end = max(beg, min(end, E));

    const uint2* plane = (const uint2*)(q + (size_t)r * ((size_t)N * DIMW));
    int wid = threadIdx.x >> 6, lane = threadIdx.x & 63;
    int e16 = lane >> 2, dp = lane & 3;
    int rowbase = wid * 8;

    float ax[8], ay[8], az[8], aw[8];
#pragma unroll
    for (int k = 0; k < 8; ++k) { ax[k] = 0.f; ay[k] = 0.f; az[k] = 0.f; aw[k] = 0.f; }

    for (int cb = beg; cb < end; cb += TCAP) {
        int cntc = min(TCAP, end - cb);
        __syncthreads();                               // protect previous chunk reads
        for (int k = threadIdx.x; k < cntc; k += 256)
            recs[k] = sorted[cb + k];
        __syncthreads();

        if (srt) {
#pragma unroll
            for (int qq = 0; qq < 8; ++qq) {
                int li = rowbase + qq;
                int gs = rp[li];
                int geR = rp[li + 1];
                int ge = (geR >= 0) ? geR : (-geR - 2);
                int jb = max(gs, cb) - cb;
                int je = min(ge, cb + cntc) - cb;
                if (jb >= je) continue;
                float sx = 0.f, sy = 0.f, sz = 0.f, sw = 0.f;
                int j = jb;
                for (; j + 32 <= je; j += 32) {        // 2 groups of 16 edges in flight
                    unsigned long long r0 = recs[j      + e16];
                    unsigned long long r1 = recs[j + 16 + e16];
                    uint2 u0 = plane[((int)((unsigned)r0 & COLMASK) << 2) | dp];
                    uint2 u1 = plane[((int)((unsigned)r1 & COLMASK) << 2) | dp];
                    float v0 = __uint_as_float((unsigned)(r0 >> 32));
                    float v1 = __uint_as_float((unsigned)(r1 >> 32));
                    sx += v0 * __uint_as_float(u0.x << 16);
                    sy += v0 * __uint_as_float(u0.x & 0xFFFF0000u);
                    sz += v0 * __uint_as_float(u0.y << 16);
                    sw += v0 * __uint_as_float(u0.y & 0xFFFF0000u);
                    sx += v1 * __uint_as_float(u1.x << 16);
                    sy += v1 * __uint_as_float(u1.x & 0xFFFF0000u);
                    sz += v1 * __uint_as_float(u1.y << 16);
                    sw += v1 * __uint_as_float(u1.y & 0xFFFF0000u);
                }
                for (; j < je; j += 16) {
                    int idx = j + e16;
                    bool m = idx < je;
                    unsigned long long r0 = recs[m ? idx : j];
                    uint2 u0 = plane[((int)((unsigned)r0 & COLMASK) << 2) | dp];
                    float v0 = m ? __uint_as_float((unsigned)(r0 >> 32)) : 0.f;
                    sx += v0 * __uint_as_float(u0.x << 16);
                    sy += v0 * __uint_as_float(u0.x & 0xFFFF0000u);
                    sz += v0 * __uint_as_float(u0.y << 16);
                    sw += v0 * __uint_as_float(u0.y & 0xFFFF0000u);
                }
                ax[qq] += sx; ay[qq] += sy; az[qq] += sz; aw[qq] += sw;
            }
        } else {
            // unsorted (oversized) bucket: predicated accumulate, correct for any order
            for (int j = 0; j < cntc; j += 16) {
                int idx = j + e16;
                bool m = idx < cntc;
                unsigned long long r0 = recs[m ? idx : j];
                unsigned lo = (unsigned)r0;
                int rl = (int)((lo >> COLBITS) & (BROWS - 1));
                uint2 u0 = plane[((int)(lo & COLMASK) << 2) | dp];
                float v0 = m ? __uint_as_float((unsigned)(r0 >> 32)) : 0.f;
                float px = v0 * __uint_as_float(u0.x << 16);
                float py = v0 * __uint_as_float(u0.x & 0xFFFF0000u);
                float pz = v0 * __uint_as_float(u0.y << 16);
                float pw = v0 * __uint_as_float(u0.y & 0xFFFF0000u);
#pragma unroll
                for (int qq = 0; qq < 8; ++qq) {
                    bool sel = rl == rowbase + qq;
                    ax[qq] += sel ? px : 0.f;
                    ay[qq] += sel ? py : 0.f;
                    az[qq] += sel ? pz : 0.f;
                    aw[qq] += sel ? pw : 0.f;
                }
            }
        }
    }

    // reduce over the 16 edge-slots (lane bits 2..5), nt-store 16 B per row-lane
#pragma unroll
    for (int qq = 0; qq < 8; ++qq) {
        float sx = ax[qq], sy = ay[qq], sz = az[qq], sw = aw[qq];
#pragma unroll
        for (int msk = 4; msk <= 32; msk <<= 1) {
            sx += __shfl_xor(sx, msk);
            sy += __shfl_xor(sy, msk);
            sz += __shfl_xor(sz, msk);
            sw += __shfl_xor(sw, msk);
        }
        int row = b * BROWS + rowbase + qq;
        if (row < N && e16 == 0) {
            vf4 p = { sx, sy, sz, sw };
            vf4* dst = (vf4*)(out + (size_t)row * D + r * 16 + dp * 4);
            __builtin_nontemporal_store(p, dst);
        }
    }
}

// ---------- Fallback phase 4 (f32 workspace-tight path): round-1 bucket kernel ----------
__global__ __launch_bounds__(256) void k_bucket2f(const int2* __restrict__ sorted,
                                                  const int* __restrict__ O,
                                                  const int* __restrict__ bs,
                                                  const float2* __restrict__ e2,
                                                  float* __restrict__ out,
                                                  int N, int nb, int E) {
    __shared__ int rowcnt[BROWS], rowoff[BROWS], rowcur[BROWS];
    __shared__ int2 rec2[CAP];
    int b  = blockIdx.x;
    int f0 = b * CHUNKS;
    int beg = O[f0] + bs[f0 >> 10];
    int end;
    if (b + 1 < nb) { int f1 = (b + 1) * CHUNKS; end = O[f1] + bs[f1 >> 10]; }
    else            end = E;
    beg = max(0, min(beg, E));
    end = max(beg, min(end, E));
    int wid = threadIdx.x >> 6, lane = threadIdx.x & 63;

    float2 acc[8];
#pragma unroll
    for (int q = 0; q < 8; ++q) acc[q] = make_float2(0.f, 0.f);

    for (int done = beg; done < end; done += CAP) {
        int cnt = min(CAP, end - done);
        if (threadIdx.x < BROWS) rowcnt[threadIdx.x] = 0;
        __syncthreads();
        for (int k = threadIdx.x; k < cnt; k += 256)
            atomicAdd(&rowcnt[(((unsigned)sorted[done + k].x) >> COLBITS) & (BROWS - 1)], 1);
        __syncthreads();
        if (threadIdx.x < BROWS) {
            int v = rowcnt[threadIdx.x];
            int incl = v;
#pragma unroll
            for (int off = 1; off < BROWS; off <<= 1) {
                int u = __shfl_up(incl, off);
                if ((int)threadIdx.x >= off) incl += u;
            }
            rowoff[threadIdx.x] = incl - v;
            rowcur[threadIdx.x] = incl - v;
        }
        __syncthreads();
        for (int k = threadIdx.x; k < cnt; k += 256) {
            int2 rr = sorted[done + k];
            int row = (((unsigned)rr.x) >> COLBITS) & (BROWS - 1);
            int pos = atomicAdd(&rowcur[row], 1);
            if (pos >= 0 && pos < CAP) rec2[pos] = rr;
        }
        __syncthreads();

#pragma unroll
        for (int q = 0; q < 8; ++q) {
            int row = wid * 8 + q;
            int off = rowoff[row], cr = rowcnt[row];
            int j = 0;
            for (; j + 4 <= cr; j += 4) {
                int2 r0 = rec2[off + j];     int2 r1 = rec2[off + j + 1];
                int2 r2 = rec2[off + j + 2]; int2 r3 = rec2[off + j + 3];
                float v0 = __int_as_float(r0.y), v1 = __int_as_float(r1.y);
                float v2 = __int_as_float(r2.y), v3 = __int_as_float(r3.y);
                float2 g0 = e2[(size_t)(r0.x & COLMASK) * 64 + lane];
                float2 g1 = e2[(size_t)(r1.x & COLMASK) * 64 + lane];
                float2 g2 = e2[(size_t)(r2.x & COLMASK) * 64 + lane];
                float2 g3 = e2[(size_t)(r3.x & COLMASK) * 64 + lane];
                acc[q].x += v0 * g0.x; acc[q].y += v0 * g0.y;
                acc[q].x += v1 * g1.x; acc[q].y += v1 * g1.y;
                acc[q].x += v2 * g2.x; acc[q].y += v2 * g2.y;
                acc[q].x += v3 * g3.x; acc[q].y += v3 * g3.y;
            }
            for (; j < cr; ++j) {
                int2 r0 = rec2[off + j];
                float v0 = __int_as_float(r0.y);
                float2 g0 = e2[(size_t)(r0.x & COLMASK) * 64 + lane];
                acc[q].x += v0 * g0.x;
                acc[q].y += v0 * g0.y;
            }
        }
        __syncthreads();
    }

    size_t rowbase = (size_t)b * BROWS;
    unsigned long long* out64 = (unsigned long long*)out;
#pragma unroll
    for (int q = 0; q < 8; ++q) {
        size_t row = rowbase + wid * 8 + q;
        if (row < (size_t)N) {
            unsigned long long p =
                ((unsigned long long)__float_as_uint(acc[q].y) << 32) |
                (unsigned long long)__float_as_uint(acc[q].x);
            __builtin_nontemporal_store(p, out64 + row * 64 + lane);
        }
    }
}

// ---------- Fallback: direct atomic scatter-add ----------
__global__ void k_atomic(const int* __restrict__ rows, const int* __restrict__ cols,
                         const float* __restrict__ vals, const float2* __restrict__ emb,
                         float* __restrict__ out, int E) {
    long long g = (long long)blockIdx.x * blockDim.x + threadIdx.x;
    int e    = (int)(g >> 6);
    int lane = (int)(g & 63);
    if (e >= E) return;
    int r = rows[e], c = cols[e];
    float v = vals[e];
    float2 em = emb[(size_t)c * (D / 2) + lane];
    atomicAdd(&out[(size_t)r * D + lane * 2    ], v * em.x);
    atomicAdd(&out[(size_t)r * D + lane * 2 + 1], v * em.y);
}

extern "C" void kernel_launch(void* const* d_in, const int* in_sizes, int n_in,
                              void* d_out, int out_size, void* d_ws, size_t ws_size,
                              hipStream_t stream) {
    const int*   adj  = (const int*)d_in[0];
    const float* vals = (const float*)d_in[1];
    const float* emb  = (const float*)d_in[2];
    int E = in_sizes[1];
    int N = in_sizes[2] / D;
    const int* rows = adj;
    const int* cols = adj + E;
    float* out = (float*)d_out;

    int nb   = (N + BROWS - 1) / BROWS;
    int CE   = (E + CHUNKS - 1) / CHUNKS;
    int flat = nb * CHUNKS;
    int nblk = (flat + 1023) / 1024;

    size_t off_sorted = 0;
    size_t sz_sorted  = (size_t)E * 8;
    size_t off_M      = (off_sorted + sz_sorted + 255) & ~(size_t)255;
    size_t sz_M       = (size_t)flat * 4;               // reused as rowptr[N+1] after scan1
    size_t off_O      = (off_M + sz_M + 255) & ~(size_t)255;
    size_t sz_O       = (size_t)flat * 4;
    size_t off_bs     = (off_O + sz_O + 255) & ~(size_t)255;
    size_t sz_bs      = (size_t)nblk * 4;
    size_t off_q      = (off_bs + sz_bs + 255) & ~(size_t)255;
    size_t sz_q       = (size_t)N * 256;                // bf16 planes: N*64 u32
    size_t need_bf16  = off_q + sz_q;
    size_t need_f32   = off_q;

    bool ok = (N > 0) && (E > 0) && (N <= (1 << COLBITS)) &&
              ((size_t)nb * 4 <= 60000) && (nblk <= 1024) &&
              (sz_M >= (size_t)(N + 1) * 4);

    if (ok && ws_size >= need_f32) {
        char* ws = (char*)d_ws;
        unsigned long long* sorted = (unsigned long long*)(ws + off_sorted);
        int* M      = (int*)(ws + off_M);
        int* rowptr = (int*)(ws + off_M);               // alias: M dead after k_scan1
        int* O      = (int*)(ws + off_O);
        int* bs     = (int*)(ws + off_bs);
        bool bf16 = (ws_size >= need_bf16);
        unsigned* q = (unsigned*)(ws + off_q);

        int cvtb = bf16 ? CVTB : 0;
        k_prep    <<<CHUNKS + cvtb, PBLK, (size_t)nb * 4, stream>>>(
                      rows, E, CE, nb, M, (const float2*)emb, q, N * 64, cvtb);
        k_scan1   <<<nblk, 1024, 0, stream>>>(M, flat, O, bs);
        k_scan2   <<<1, 1024, 0, stream>>>(bs, nblk);
        k_mscatter<<<CHUNKS, PBLK, (size_t)nb * 4, stream>>>(
                      rows, cols, vals, E, CE, nb, O, bs, sorted);
        if (bf16) {
            k_rowsort<<<nb, 256, 0, stream>>>(sorted, O, bs, rowptr, nb, N, E);
            // grid = nb*8: blockIdx&7 = dim-plane = XCD (round-robin dispatch)
            k_dimtile<<<nb * DSPLIT, 256, 0, stream>>>(sorted, rowptr, q, out, N, E);
        } else {
            k_bucket2f<<<nb, 256, 0, stream>>>((const int2*)sorted, O, bs,
                                               (const float2*)emb, out, N, nb, E);
        }
    } else {
        hipMemsetAsync(out, 0, (size_t)out_size * sizeof(float), stream);
        long long tot = (long long)E * 64;
        int blocks = (int)((tot + 255) / 256);
        k_atomic<<<blocks, 256, 0, stream>>>(rows, cols, vals, (const float2*)emb, out, E);
    }
}

// Round 9
// 425.987 us; speedup vs baseline: 1.0364x; 1.0364x over previous
//
#include <hip/hip_runtime.h>

#define D 128
#define BROWS 32
#define BSHIFT 5
#define COLBITS 17
#define COLMASK 0x1FFFF
#define CHUNKS 256
#define CAP 1280
#define CVTB 1792
#define PBLK 1024
#define DSPLIT 8      // embedding-dim split: 8 planes of 16 dims (3.3 MB each -> L2-resident per XCD)
#define DIMW 8        // u32 words (2 bf16 dims each) per plane per node
#define RSCAP 4096    // max bucket run sorted in-place via LDS (mean 1024, sigma 32)
#define TCAP 1536     // phase-4 LDS staging chunk (12 KB)
// XCD-grouping permutation of chunk->matrix-slot (valid for CHUNKS==256)
#define PERM(c) ((((c) & 7) << 5) | ((c) >> 3))

// ---------- Phase 1 (fused): per-chunk bucket histogram + emb fp32->bf16 plane convert ----------
__global__ void k_prep(const int* __restrict__ rows, int E, int CE, int nb,
                       int* __restrict__ M,
                       const float2* __restrict__ emb, unsigned* __restrict__ q,
                       int n, int cvtb) {
    int histBlocks = gridDim.x - cvtb;
    if ((int)blockIdx.x >= histBlocks) {
        int stride = cvtb * PBLK;
        size_t planeWords = (size_t)(n >> 3);          // N*8 words per plane
        for (int i = ((int)blockIdx.x - histBlocks) * PBLK + threadIdx.x; i < n; i += stride) {
            float2 f = emb[i];
            unsigned lo = __float_as_uint(f.x), hi = __float_as_uint(f.y);
            lo = (lo + 0x7FFFu + ((lo >> 16) & 1u)) & 0xFFFF0000u;   // RNE to bf16
            hi = (hi + 0x7FFFu + ((hi >> 16) & 1u)) & 0xFFFF0000u;
            size_t plane = (size_t)((i >> 3) & 7);
            size_t w     = (size_t)(((i >> 6) << 3) | (i & 7));
            q[plane * planeWords + w] = hi | (lo >> 16);
        }
        return;
    }
    extern __shared__ int h[];
    int c = blockIdx.x;
    int slot = PERM(c);
    for (int i = threadIdx.x; i < nb; i += PBLK) h[i] = 0;
    __syncthreads();
    int beg = c * CE, end = min(E, beg + CE);
    for (int e = beg + threadIdx.x; e < end; e += PBLK)
        atomicAdd(&h[rows[e] >> BSHIFT], 1);            // int LDS atomic: native ds_add
    __syncthreads();
    for (int i = threadIdx.x; i < nb; i += PBLK) M[(size_t)i * CHUNKS + slot] = h[i];
}

// ---------- Phase 2: hierarchical exclusive scan ----------
__global__ void k_scan1(const int* __restrict__ M, int flat,
                        int* __restrict__ O, int* __restrict__ bs) {
    __shared__ int s[1024];
    int i = blockIdx.x * 1024 + threadIdx.x;
    int v = (i < flat) ? M[i] : 0;
    s[threadIdx.x] = v;
    __syncthreads();
    for (int off = 1; off < 1024; off <<= 1) {
        int t = (threadIdx.x >= (unsigned)off) ? s[threadIdx.x - off] : 0;
        __syncthreads();
        s[threadIdx.x] += t;
        __syncthreads();
    }
    if (i < flat) O[i] = s[threadIdx.x] - v;
    if (threadIdx.x == 1023) bs[blockIdx.x] = s[1023];
}

__global__ void k_scan2(int* __restrict__ bs, int nblk) {
    __shared__ int s[1024];
    __shared__ int carry;
    if (threadIdx.x == 0) carry = 0;
    __syncthreads();
    for (int base = 0; base < nblk; base += 1024) {
        int i = base + (int)threadIdx.x;
        int v = (i < nblk) ? bs[i] : 0;
        s[threadIdx.x] = v;
        __syncthreads();
        for (int off = 1; off < 1024; off <<= 1) {
            int t = (threadIdx.x >= (unsigned)off) ? s[threadIdx.x - off] : 0;
            __syncthreads();
            s[threadIdx.x] += t;
            __syncthreads();
        }
        int c = carry;
        if (i < nblk) bs[i] = c + s[threadIdx.x] - v;
        __syncthreads();
        if (threadIdx.x == 0) carry = c + s[1023];
        __syncthreads();
    }
}

// ---------- Phase 3: bucket-sorted scatter via LDS cursors (proven round-1) ----------
__global__ void k_mscatter(const int* __restrict__ rows, const int* __restrict__ cols,
                           const float* __restrict__ vals, int E, int CE, int nb,
                           const int* __restrict__ O, const int* __restrict__ bs,
                           unsigned long long* __restrict__ sorted) {
    extern __shared__ int cur[];
    int c = blockIdx.x;
    int slot = PERM(c);
    for (int b = threadIdx.x; b < nb; b += PBLK) {
        int f = b * CHUNKS + slot;
        cur[b] = O[f] + bs[f >> 10];
    }
    __syncthreads();
    int beg = c * CE, end = min(E, beg + CE);
    for (int e = beg + threadIdx.x; e < end; e += PBLK) {
        int r = rows[e];
        int b = r >> BSHIFT;
        int pos = atomicAdd(&cur[b], 1);
        unsigned packed = ((unsigned)(r & (BROWS - 1)) << COLBITS) | (unsigned)cols[e];
        unsigned long long rec =
            ((unsigned long long)__float_as_uint(vals[e]) << 32) | (unsigned long long)packed;
        if (pos >= 0 && pos < E)
            sorted[pos] = rec;
    }
}

// ---------- Phase 3.5: per-bucket in-place row sort + global CSR rowptr ----------
// Staging read is NONTEMPORAL: the pre-sort ordering is dead after this kernel,
// keep it from polluting L2.
__global__ __launch_bounds__(256) void k_rowsort(unsigned long long* __restrict__ sorted,
                                                 const int* __restrict__ O,
                                                 const int* __restrict__ bs,
                                                 int* __restrict__ rowptr,
                                                 int nb, int N, int E) {
    __shared__ unsigned long long recs[RSCAP];
    __shared__ int cnt[BROWS], cur[BROWS];
    int b = blockIdx.x;
    int f0 = b * CHUNKS;
    int beg = O[f0] + bs[f0 >> 10];
    int end;
    if (b + 1 < nb) { int f1 = (b + 1) * CHUNKS; end = O[f1] + bs[f1 >> 10]; }
    else            end = E;
    beg = max(0, min(beg, E));
    end = max(beg, min(end, E));
    int run = end - beg;
    if (b == 0 && threadIdx.x == 0) rowptr[N] = E;
    if (run > RSCAP) {
        if (threadIdx.x < BROWS) {
            int row = b * BROWS + (int)threadIdx.x;
            if (row < N) rowptr[row] = -beg - 2;       // sentinel, decodes bucket start
        }
        return;
    }
    if (threadIdx.x < BROWS) cnt[threadIdx.x] = 0;
    for (int k = threadIdx.x; k < run; k += 256)
        recs[k] = __builtin_nontemporal_load(sorted + beg + k);
    __syncthreads();
    for (int k = threadIdx.x; k < run; k += 256)
        atomicAdd(&cnt[((unsigned)recs[k] >> COLBITS) & (BROWS - 1)], 1);
    __syncthreads();
    if (threadIdx.x < BROWS) {
        int v = cnt[threadIdx.x];
        int incl = v;
#pragma unroll
        for (int off = 1; off < BROWS; off <<= 1) {
            int u = __shfl_up(incl, off);
            if ((int)threadIdx.x >= off) incl += u;
        }
        int excl = incl - v;
        cur[threadIdx.x] = excl;
        int row = b * BROWS + (int)threadIdx.x;
        if (row < N) rowptr[row] = beg + excl;
    }
    __syncthreads();
    for (int k = threadIdx.x; k < run; k += 256) {
        unsigned long long rc = recs[k];
        int row = ((unsigned)rc >> COLBITS) & (BROWS - 1);
        int pos = atomicAdd(&cur[row], 1);
        if (pos >= 0 && pos < run) sorted[beg + pos] = rc;
    }
}

// ---------- Phase 4: dim-sliced, LDS-staged row-run streaming (round-4 proven layout) ----------
// Block (bucket b, plane r=blockIdx&7) computes out[b*32..+32)[16r..16r+16).
// Lane layout: e8 = lane>>3 (8 edges in flight), dw = lane&7 (one u32 = 2 bf16 dims);
// 4 gather groups in flight per row (MLP matters: mean row = 32 edges).
// Staging loads are NONTEMPORAL so the 26 MB sorted stream doesn't evict the
// 3.3 MB XCD-local plane from L2 (FETCH_SIZE showed plane eviction misses).
__global__ __launch_bounds__(256) void k_dimtile(const unsigned long long* __restrict__ sorted,
                                                 const int* __restrict__ rowptr,
                                                 const unsigned* __restrict__ q,
                                                 float* __restrict__ out,
                                                 int N, int E) {
    __shared__ unsigned long long recs[TCAP];
    __shared__ int rp[BROWS + 1];
    int r = blockIdx.x & (DSPLIT - 1);
    int b = blockIdx.x >> 3;
    if (threadIdx.x <= BROWS) {
        int row = b * BROWS + (int)threadIdx.x;
        rp[threadIdx.x] = (row <= N) ? rowptr[row] : E;
    }
    __syncthreads();
    int rp0 = rp[0];
    bool srt = rp0 >= 0;                               // sorted bucket?
    int beg = srt ? rp0 : (-rp0 - 2);
    int endv = rp[BROWS];
    int end = (endv >= 0) ? endv : (-endv - 2);
    beg = max(0, min(beg, E));
    end = max(beg, min(end, E));

    const unsigned* plane = q + (size_t)r * ((size_t)N * DIMW);
    int wid = threadIdx.x >> 6, lane = threadIdx.x & 63;
    int e8 = lane >> 3, dw = lane & 7;
    int rowbase = wid * 8;

    float ax[8], ay[8];
#pragma unroll
    for (int k = 0; k < 8; ++k) { ax[k] = 0.f; ay[k] = 0.f; }

    for (int cb = beg; cb < end; cb += TCAP) {
        int cntc = min(TCAP, end - cb);
        __syncthreads();                               // protect previous chunk reads
        for (int k = threadIdx.x; k < cntc; k += 256)
            recs[k] = __builtin_nontemporal_load(sorted + cb + k);
        __syncthreads();

        if (srt) {
#pragma unroll
            for (int qq = 0; qq < 8; ++qq) {
                int li = rowbase + qq;
                int gs = rp[li];
                int geR = rp[li + 1];
                int ge = (geR >= 0) ? geR : (-geR - 2);
                int jb = max(gs, cb) - cb;
                int je = min(ge, cb + cntc) - cb;
                if (jb >= je) continue;
                float sx = 0.f, sy = 0.f;
                int j = jb;
                for (; j + 32 <= je; j += 32) {        // 4 groups of 8 edges in flight
                    unsigned long long r0 = recs[j      + e8];
                    unsigned long long r1 = recs[j +  8 + e8];
                    unsigned long long r2 = recs[j + 16 + e8];
                    unsigned long long r3 = recs[j + 24 + e8];
                    unsigned u0 = plane[(size_t)((unsigned)r0 & COLMASK) * DIMW + dw];
                    unsigned u1 = plane[(size_t)((unsigned)r1 & COLMASK) * DIMW + dw];
                    unsigned u2 = plane[(size_t)((unsigned)r2 & COLMASK) * DIMW + dw];
                    unsigned u3 = plane[(size_t)((unsigned)r3 & COLMASK) * DIMW + dw];
                    float v0 = __uint_as_float((unsigned)(r0 >> 32));
                    float v1 = __uint_as_float((unsigned)(r1 >> 32));
                    float v2 = __uint_as_float((unsigned)(r2 >> 32));
                    float v3 = __uint_as_float((unsigned)(r3 >> 32));
                    sx += v0 * __uint_as_float(u0 << 16);  sy += v0 * __uint_as_float(u0 & 0xFFFF0000u);
                    sx += v1 * __uint_as_float(u1 << 16);  sy += v1 * __uint_as_float(u1 & 0xFFFF0000u);
                    sx += v2 * __uint_as_float(u2 << 16);  sy += v2 * __uint_as_float(u2 & 0xFFFF0000u);
                    sx += v3 * __uint_as_float(u3 << 16);  sy += v3 * __uint_as_float(u3 & 0xFFFF0000u);
                }
                for (; j < je; j += 8) {
                    int idx = j + e8;
                    bool m = idx < je;
                    unsigned long long r0 = recs[m ? idx : j];
                    unsigned u0 = plane[(size_t)((unsigned)r0 & COLMASK) * DIMW + dw];
                    float v0 = m ? __uint_as_float((unsigned)(r0 >> 32)) : 0.f;
                    sx += v0 * __uint_as_float(u0 << 16);
                    sy += v0 * __uint_as_float(u0 & 0xFFFF0000u);
                }
                ax[qq] += sx; ay[qq] += sy;
            }
        } else {
            // unsorted (oversized) bucket: predicated accumulate, correct for any order
            for (int j = 0; j < cntc; j += 8) {
                int idx = j + e8;
                bool m = idx < cntc;
                unsigned long long r0 = recs[m ? idx : j];
                unsigned lo = (unsigned)r0;
                int rl = (int)((lo >> COLBITS) & (BROWS - 1));
                unsigned u0 = plane[(size_t)(lo & COLMASK) * DIMW + dw];
                float v0 = m ? __uint_as_float((unsigned)(r0 >> 32)) : 0.f;
                float px = v0 * __uint_as_float(u0 << 16);
                float py = v0 * __uint_as_float(u0 & 0xFFFF0000u);
#pragma unroll
                for (int qq = 0; qq < 8; ++qq) {
                    bool sel = rl == rowbase + qq;
                    ax[qq] += sel ? px : 0.f;
                    ay[qq] += sel ? py : 0.f;
                }
            }
        }
    }

    // reduce over the 8 edge-slots (lane bits 3..5), nt-store 8 B per row
    unsigned long long* out64 = (unsigned long long*)out;
#pragma unroll
    for (int qq = 0; qq < 8; ++qq) {
        float sx = ax[qq], sy = ay[qq];
        sx += __shfl_xor(sx, 8);  sy += __shfl_xor(sy, 8);
        sx += __shfl_xor(sx, 16); sy += __shfl_xor(sy, 16);
        sx += __shfl_xor(sx, 32); sy += __shfl_xor(sy, 32);
        int row = b * BROWS + rowbase + qq;
        if (row < N && e8 == 0) {
            unsigned long long p =
                ((unsigned long long)__float_as_uint(sy) << 32) |
                (unsigned long long)__float_as_uint(sx);
            __builtin_nontemporal_store(p, out64 + (size_t)row * 64 + r * DIMW + dw);
        }
    }
}

// ---------- Fallback phase 4 (f32 workspace-tight path): round-1 bucket kernel ----------
__global__ __launch_bounds__(256) void k_bucket2f(const int2* __restrict__ sorted,
                                                  const int* __restrict__ O,
                                                  const int* __restrict__ bs,
                                                  const float2* __restrict__ e2,
                                                  float* __restrict__ out,
                                                  int N, int nb, int E) {
    __shared__ int rowcnt[BROWS], rowoff[BROWS], rowcur[BROWS];
    __shared__ int2 rec2[CAP];
    int b  = blockIdx.x;
    int f0 = b * CHUNKS;
    int beg = O[f0] + bs[f0 >> 10];
    int end;
    if (b + 1 < nb) { int f1 = (b + 1) * CHUNKS; end = O[f1] + bs[f1 >> 10]; }
    else            end = E;
    beg = max(0, min(beg, E));
    end = max(beg, min(end, E));
    int wid = threadIdx.x >> 6, lane = threadIdx.x & 63;

    float2 acc[8];
#pragma unroll
    for (int q = 0; q < 8; ++q) acc[q] = make_float2(0.f, 0.f);

    for (int done = beg; done < end; done += CAP) {
        int cnt = min(CAP, end - done);
        if (threadIdx.x < BROWS) rowcnt[threadIdx.x] = 0;
        __syncthreads();
        for (int k = threadIdx.x; k < cnt; k += 256)
            atomicAdd(&rowcnt[(((unsigned)sorted[done + k].x) >> COLBITS) & (BROWS - 1)], 1);
        __syncthreads();
        if (threadIdx.x < BROWS) {
            int v = rowcnt[threadIdx.x];
            int incl = v;
#pragma unroll
            for (int off = 1; off < BROWS; off <<= 1) {
                int u = __shfl_up(incl, off);
                if ((int)threadIdx.x >= off) incl += u;
            }
            rowoff[threadIdx.x] = incl - v;
            rowcur[threadIdx.x] = incl - v;
        }
        __syncthreads();
        for (int k = threadIdx.x; k < cnt; k += 256) {
            int2 rr = sorted[done + k];
            int row = (((unsigned)rr.x) >> COLBITS) & (BROWS - 1);
            int pos = atomicAdd(&rowcur[row], 1);
            if (pos >= 0 && pos < CAP) rec2[pos] = rr;
        }
        __syncthreads();

#pragma unroll
        for (int q = 0; q < 8; ++q) {
            int row = wid * 8 + q;
            int off = rowoff[row], cr = rowcnt[row];
            int j = 0;
            for (; j + 4 <= cr; j += 4) {
                int2 r0 = rec2[off + j];     int2 r1 = rec2[off + j + 1];
                int2 r2 = rec2[off + j + 2]; int2 r3 = rec2[off + j + 3];
                float v0 = __int_as_float(r0.y), v1 = __int_as_float(r1.y);
                float v2 = __int_as_float(r2.y), v3 = __int_as_float(r3.y);
                float2 g0 = e2[(size_t)(r0.x & COLMASK) * 64 + lane];
                float2 g1 = e2[(size_t)(r1.x & COLMASK) * 64 + lane];
                float2 g2 = e2[(size_t)(r2.x & COLMASK) * 64 + lane];
                float2 g3 = e2[(size_t)(r3.x & COLMASK) * 64 + lane];
                acc[q].x += v0 * g0.x; acc[q].y += v0 * g0.y;
                acc[q].x += v1 * g1.x; acc[q].y += v1 * g1.y;
                acc[q].x += v2 * g2.x; acc[q].y += v2 * g2.y;
                acc[q].x += v3 * g3.x; acc[q].y += v3 * g3.y;
            }
            for (; j < cr; ++j) {
                int2 r0 = rec2[off + j];
                float v0 = __int_as_float(r0.y);
                float2 g0 = e2[(size_t)(r0.x & COLMASK) * 64 + lane];
                acc[q].x += v0 * g0.x;
                acc[q].y += v0 * g0.y;
            }
        }
        __syncthreads();
    }

    size_t rowbase = (size_t)b * BROWS;
    unsigned long long* out64 = (unsigned long long*)out;
#pragma unroll
    for (int q = 0; q < 8; ++q) {
        size_t row = rowbase + wid * 8 + q;
        if (row < (size_t)N) {
            unsigned long long p =
                ((unsigned long long)__float_as_uint(acc[q].y) << 32) |
                (unsigned long long)__float_as_uint(acc[q].x);
            __builtin_nontemporal_store(p, out64 + row * 64 + lane);
        }
    }
}

// ---------- Fallback: direct atomic scatter-add ----------
__global__ void k_atomic(const int* __restrict__ rows, const int* __restrict__ cols,
                         const float* __restrict__ vals, const float2* __restrict__ emb,
                         float* __restrict__ out, int E) {
    long long g = (long long)blockIdx.x * blockDim.x + threadIdx.x;
    int e    = (int)(g >> 6);
    int lane = (int)(g & 63);
    if (e >= E) return;
    int r = rows[e], c = cols[e];
    float v = vals[e];
    float2 em = emb[(size_t)c * (D / 2) + lane];
    atomicAdd(&out[(size_t)r * D + lane * 2    ], v * em.x);
    atomicAdd(&out[(size_t)r * D + lane * 2 + 1], v * em.y);
}

extern "C" void kernel_launch(void* const* d_in, const int* in_sizes, int n_in,
                              void* d_out, int out_size, void* d_ws, size_t ws_size,
                              hipStream_t stream) {
    const int*   adj  = (const int*)d_in[0];
    const float* vals = (const float*)d_in[1];
    const float* emb  = (const float*)d_in[2];
    int E = in_sizes[1];
    int N = in_sizes[2] / D;
    const int* rows = adj;
    const int* cols = adj + E;
    float* out = (float*)d_out;

    int nb   = (N + BROWS - 1) / BROWS;
    int CE   = (E + CHUNKS - 1) / CHUNKS;
    int flat = nb * CHUNKS;
    int nblk = (flat + 1023) / 1024;

    size_t off_sorted = 0;
    size_t sz_sorted  = (size_t)E * 8;
    size_t off_M      = (off_sorted + sz_sorted + 255) & ~(size_t)255;
    size_t sz_M       = (size_t)flat * 4;               // reused as rowptr[N+1] after scan1
    size_t off_O      = (off_M + sz_M + 255) & ~(size_t)255;
    size_t sz_O       = (size_t)flat * 4;
    size_t off_bs     = (off_O + sz_O + 255) & ~(size_t)255;
    size_t sz_bs      = (size_t)nblk * 4;
    size_t off_q      = (off_bs + sz_bs + 255) & ~(size_t)255;
    size_t sz_q       = (size_t)N * 256;                // bf16 planes: N*64 u32
    size_t need_bf16  = off_q + sz_q;
    size_t need_f32   = off_q;

    bool ok = (N > 0) && (E > 0) && (N <= (1 << COLBITS)) &&
              ((size_t)nb * 4 <= 60000) && (nblk <= 1024) &&
              (sz_M >= (size_t)(N + 1) * 4);

    if (ok && ws_size >= need_f32) {
        char* ws = (char*)d_ws;
        unsigned long long* sorted = (unsigned long long*)(ws + off_sorted);
        int* M      = (int*)(ws + off_M);
        int* rowptr = (int*)(ws + off_M);               // alias: M dead after k_scan1
        int* O      = (int*)(ws + off_O);
        int* bs     = (int*)(ws + off_bs);
        bool bf16 = (ws_size >= need_bf16);
        unsigned* q = (unsigned*)(ws + off_q);

        int cvtb = bf16 ? CVTB : 0;
        k_prep    <<<CHUNKS + cvtb, PBLK, (size_t)nb * 4, stream>>>(
                      rows, E, CE, nb, M, (const float2*)emb, q, N * 64, cvtb);
        k_scan1   <<<nblk, 1024, 0, stream>>>(M, flat, O, bs);
        k_scan2   <<<1, 1024, 0, stream>>>(bs, nblk);
        k_mscatter<<<CHUNKS, PBLK, (size_t)nb * 4, stream>>>(
                      rows, cols, vals, E, CE, nb, O, bs, sorted);
        if (bf16) {
            k_rowsort<<<nb, 256, 0, stream>>>(sorted, O, bs, rowptr, nb, N, E);
            // grid = nb*8: blockIdx&7 = dim-plane = XCD (round-robin dispatch)
            k_dimtile<<<nb * DSPLIT, 256, 0, stream>>>(sorted, rowptr, q, out, N, E);
        } else {
            k_bucket2f<<<nb, 256, 0, stream>>>((const int2*)sorted, O, bs,
                                               (const float2*)emb, out, N, nb, E);
        }
    } else {
        hipMemsetAsync(out, 0, (size_t)out_size * sizeof(float), stream);
        long long tot = (long long)E * 64;
        int blocks = (int)((tot + 255) / 256);
        k_atomic<<<blocks, 256, 0, stream>>>(rows, cols, vals, (const float2*)emb, out, E);
    }
}

// Round 11
// 345.632 us; speedup vs baseline: 1.2774x; 1.2325x over previous
//
#include <hip/hip_runtime.h>

#define D 128
#define BROWS 32
#define BSHIFT 5
#define COLBITS 17
#define COLMASK 0x1FFFF
#define CHUNKS 256
#define CAP 1280
#define CVTB 1792
#define PBLK 1024
// XCD-grouping permutation of chunk->matrix-slot (valid for CHUNKS==256)
#define PERM(c) ((((c) & 7) << 5) | ((c) >> 3))

typedef float vf4 __attribute__((ext_vector_type(4)));   // nontemporal-store-legal 16B vector

// ---------- Phase 1 (fused): per-chunk bucket histogram + emb fp32->bf16x2 (node-major) ----------
__global__ void k_prep(const int* __restrict__ rows, int E, int CE, int nb,
                       int* __restrict__ M,
                       const float2* __restrict__ emb, unsigned* __restrict__ q,
                       int n, int cvtb) {
    int histBlocks = gridDim.x - cvtb;
    if ((int)blockIdx.x >= histBlocks) {
        int stride = cvtb * PBLK;
        for (int i = ((int)blockIdx.x - histBlocks) * PBLK + threadIdx.x; i < n; i += stride) {
            float2 f = emb[i];
            unsigned lo = __float_as_uint(f.x), hi = __float_as_uint(f.y);
            lo = (lo + 0x7FFFu + ((lo >> 16) & 1u)) & 0xFFFF0000u;   // RNE to bf16
            hi = (hi + 0x7FFFu + ((hi >> 16) & 1u)) & 0xFFFF0000u;
            q[i] = hi | (lo >> 16);                     // node-major: q[node*64 + pair]
        }
        return;
    }
    extern __shared__ int h[];
    int c = blockIdx.x;
    int slot = PERM(c);
    for (int i = threadIdx.x; i < nb; i += PBLK) h[i] = 0;
    __syncthreads();
    int beg = c * CE, end = min(E, beg + CE);
    for (int e = beg + threadIdx.x; e < end; e += PBLK)
        atomicAdd(&h[rows[e] >> BSHIFT], 1);
    __syncthreads();
    for (int i = threadIdx.x; i < nb; i += PBLK) M[(size_t)i * CHUNKS + slot] = h[i];
}

// ---------- Phase 2: hierarchical exclusive scan ----------
__global__ void k_scan1(const int* __restrict__ M, int flat,
                        int* __restrict__ O, int* __restrict__ bs) {
    __shared__ int s[1024];
    int i = blockIdx.x * 1024 + threadIdx.x;
    int v = (i < flat) ? M[i] : 0;
    s[threadIdx.x] = v;
    __syncthreads();
    for (int off = 1; off < 1024; off <<= 1) {
        int t = (threadIdx.x >= (unsigned)off) ? s[threadIdx.x - off] : 0;
        __syncthreads();
        s[threadIdx.x] += t;
        __syncthreads();
    }
    if (i < flat) O[i] = s[threadIdx.x] - v;
    if (threadIdx.x == 1023) bs[blockIdx.x] = s[1023];
}

__global__ void k_scan2(int* __restrict__ bs, int nblk) {
    __shared__ int s[1024];
    __shared__ int carry;
    if (threadIdx.x == 0) carry = 0;
    __syncthreads();
    for (int base = 0; base < nblk; base += 1024) {
        int i = base + (int)threadIdx.x;
        int v = (i < nblk) ? bs[i] : 0;
        s[threadIdx.x] = v;
        __syncthreads();
        for (int off = 1; off < 1024; off <<= 1) {
            int t = (threadIdx.x >= (unsigned)off) ? s[threadIdx.x - off] : 0;
            __syncthreads();
            s[threadIdx.x] += t;
            __syncthreads();
        }
        int c = carry;
        if (i < nblk) bs[i] = c + s[threadIdx.x] - v;
        __syncthreads();
        if (threadIdx.x == 0) carry = c + s[1023];
        __syncthreads();
    }
}

// ---------- Phase 3: bucket-sorted scatter via LDS cursors ----------
__global__ void k_mscatter(const int* __restrict__ rows, const int* __restrict__ cols,
                           const float* __restrict__ vals, int E, int CE, int nb,
                           const int* __restrict__ O, const int* __restrict__ bs,
                           unsigned long long* __restrict__ sorted) {
    extern __shared__ int cur[];
    int c = blockIdx.x;
    int slot = PERM(c);
    for (int b = threadIdx.x; b < nb; b += PBLK) {
        int f = b * CHUNKS + slot;
        cur[b] = O[f] + bs[f >> 10];
    }
    __syncthreads();
    int beg = c * CE, end = min(E, beg + CE);
    for (int e = beg + threadIdx.x; e < end; e += PBLK) {
        int r = rows[e];
        int b = r >> BSHIFT;
        int pos = atomicAdd(&cur[b], 1);
        unsigned packed = ((unsigned)(r & (BROWS - 1)) << COLBITS) | (unsigned)cols[e];
        unsigned long long rec =
            ((unsigned long long)__float_as_uint(vals[e]) << 32) | (unsigned long long)packed;
        if (pos >= 0 && pos < E)
            sorted[pos] = rec;
    }
}

// ---------- Phase 4 (bf16): per-bucket LDS counting sort + uint2 (8B/lane) gathers ----------
// One block per bucket, full D=128. Each edge's 256 B row is fetched by 32 lanes
// (uint2 = 4 bf16 dims/lane); a wave-load covers 2 edges -> 8 loads in flight span
// 16 edges (2x bytes in flight vs round-0's 4B/lane, ~40% fewer instrs, same lines).
__global__ __launch_bounds__(256) void k_bucket2b(const int2* __restrict__ sorted,
                                                  const int* __restrict__ O,
                                                  const int* __restrict__ bs,
                                                  const unsigned* __restrict__ embp,
                                                  float* __restrict__ out,
                                                  int N, int nb, int E) {
    __shared__ int rowcnt[BROWS], rowoff[BROWS], rowcur[BROWS];
    __shared__ int2 rec2[CAP];
    int b  = blockIdx.x;
    int f0 = b * CHUNKS;
    int beg = O[f0] + bs[f0 >> 10];
    int end;
    if (b + 1 < nb) { int f1 = (b + 1) * CHUNKS; end = O[f1] + bs[f1 >> 10]; }
    else            end = E;
    beg = max(0, min(beg, E));
    end = max(beg, min(end, E));
    int wid = threadIdx.x >> 6, lane = threadIdx.x & 63;
    int half = lane >> 5, lh = lane & 31;

    const uint2* eq2 = (const uint2*)embp;              // node row = 32 uint2 (256 B)

    float ax[8], ay[8], az[8], aw[8];
#pragma unroll
    for (int k = 0; k < 8; ++k) { ax[k] = 0.f; ay[k] = 0.f; az[k] = 0.f; aw[k] = 0.f; }

    for (int done = beg; done < end; done += CAP) {
        int cnt = min(CAP, end - done);
        if (threadIdx.x < BROWS) rowcnt[threadIdx.x] = 0;
        __syncthreads();
        for (int k = threadIdx.x; k < cnt; k += 256)
            atomicAdd(&rowcnt[(((unsigned)sorted[done + k].x) >> COLBITS) & (BROWS - 1)], 1);
        __syncthreads();
        if (threadIdx.x < BROWS) {
            int v = rowcnt[threadIdx.x];
            int incl = v;
#pragma unroll
            for (int off = 1; off < BROWS; off <<= 1) {
                int u = __shfl_up(incl, off);
                if ((int)threadIdx.x >= off) incl += u;
            }
            rowoff[threadIdx.x] = incl - v;
            rowcur[threadIdx.x] = incl - v;
        }
        __syncthreads();
        for (int k = threadIdx.x; k < cnt; k += 256) {
            int2 rr = sorted[done + k];
            int row = (((unsigned)rr.x) >> COLBITS) & (BROWS - 1);
            int pos = atomicAdd(&rowcur[row], 1);
            if (pos >= 0 && pos < CAP) rec2[pos] = rr;
        }
        __syncthreads();

#pragma unroll
        for (int qq = 0; qq < 8; ++qq) {               // 8 rows per wave
            int row = wid * 8 + qq;
            int off = rowoff[row], cr = rowcnt[row];
            float sx = 0.f, sy = 0.f, sz = 0.f, sw = 0.f;
            int j = 0;
            for (; j + 16 <= cr; j += 16) {            // 8 loads in flight, 16 edges
                int2 r0 = rec2[off + j      + half];
                int2 r1 = rec2[off + j +  2 + half];
                int2 r2 = rec2[off + j +  4 + half];
                int2 r3 = rec2[off + j +  6 + half];
                int2 r4 = rec2[off + j +  8 + half];
                int2 r5 = rec2[off + j + 10 + half];
                int2 r6 = rec2[off + j + 12 + half];
                int2 r7 = rec2[off + j + 14 + half];
                uint2 u0 = eq2[(size_t)(r0.x & COLMASK) * 32 + lh];
                uint2 u1 = eq2[(size_t)(r1.x & COLMASK) * 32 + lh];
                uint2 u2 = eq2[(size_t)(r2.x & COLMASK) * 32 + lh];
                uint2 u3 = eq2[(size_t)(r3.x & COLMASK) * 32 + lh];
                uint2 u4 = eq2[(size_t)(r4.x & COLMASK) * 32 + lh];
                uint2 u5 = eq2[(size_t)(r5.x & COLMASK) * 32 + lh];
                uint2 u6 = eq2[(size_t)(r6.x & COLMASK) * 32 + lh];
                uint2 u7 = eq2[(size_t)(r7.x & COLMASK) * 32 + lh];
                float v0 = __int_as_float(r0.y), v1 = __int_as_float(r1.y);
                float v2 = __int_as_float(r2.y), v3 = __int_as_float(r3.y);
                float v4 = __int_as_float(r4.y), v5 = __int_as_float(r5.y);
                float v6 = __int_as_float(r6.y), v7 = __int_as_float(r7.y);
                sx += v0 * __uint_as_float(u0.x << 16);  sy += v0 * __uint_as_float(u0.x & 0xFFFF0000u);
                sz += v0 * __uint_as_float(u0.y << 16);  sw += v0 * __uint_as_float(u0.y & 0xFFFF0000u);
                sx += v1 * __uint_as_float(u1.x << 16);  sy += v1 * __uint_as_float(u1.x & 0xFFFF0000u);
                sz += v1 * __uint_as_float(u1.y << 16);  sw += v1 * __uint_as_float(u1.y & 0xFFFF0000u);
                sx += v2 * __uint_as_float(u2.x << 16);  sy += v2 * __uint_as_float(u2.x & 0xFFFF0000u);
                sz += v2 * __uint_as_float(u2.y << 16);  sw += v2 * __uint_as_float(u2.y & 0xFFFF0000u);
                sx += v3 * __uint_as_float(u3.x << 16);  sy += v3 * __uint_as_float(u3.x & 0xFFFF0000u);
                sz += v3 * __uint_as_float(u3.y << 16);  sw += v3 * __uint_as_float(u3.y & 0xFFFF0000u);
                sx += v4 * __uint_as_float(u4.x << 16);  sy += v4 * __uint_as_float(u4.x & 0xFFFF0000u);
                sz += v4 * __uint_as_float(u4.y << 16);  sw += v4 * __uint_as_float(u4.y & 0xFFFF0000u);
                sx += v5 * __uint_as_float(u5.x << 16);  sy += v5 * __uint_as_float(u5.x & 0xFFFF0000u);
                sz += v5 * __uint_as_float(u5.y << 16);  sw += v5 * __uint_as_float(u5.y & 0xFFFF0000u);
                sx += v6 * __uint_as_float(u6.x << 16);  sy += v6 * __uint_as_float(u6.x & 0xFFFF0000u);
                sz += v6 * __uint_as_float(u6.y << 16);  sw += v6 * __uint_as_float(u6.y & 0xFFFF0000u);
                sx += v7 * __uint_as_float(u7.x << 16);  sy += v7 * __uint_as_float(u7.x & 0xFFFF0000u);
                sz += v7 * __uint_as_float(u7.y << 16);  sw += v7 * __uint_as_float(u7.y & 0xFFFF0000u);
            }
            for (; j < cr; j += 2) {                   // masked 2-edge tail
                int idx = j + half;
                bool m = idx < cr;
                int2 r0 = rec2[off + (m ? idx : j)];
                uint2 u0 = eq2[(size_t)(r0.x & COLMASK) * 32 + lh];
                float v0 = m ? __int_as_float(r0.y) : 0.f;
                sx += v0 * __uint_as_float(u0.x << 16);  sy += v0 * __uint_as_float(u0.x & 0xFFFF0000u);
                sz += v0 * __uint_as_float(u0.y << 16);  sw += v0 * __uint_as_float(u0.y & 0xFFFF0000u);
            }
            ax[qq] += sx; ay[qq] += sy; az[qq] += sz; aw[qq] += sw;
        }
        __syncthreads();
    }

    // cross-half reduce (shfl_xor 32), then nt-store float4/lane: 32 lanes x 16 B = full row
    size_t rowbase = (size_t)b * BROWS;
#pragma unroll
    for (int qq = 0; qq < 8; ++qq) {
        float sx = ax[qq], sy = ay[qq], sz = az[qq], sw = aw[qq];
        sx += __shfl_xor(sx, 32);
        sy += __shfl_xor(sy, 32);
        sz += __shfl_xor(sz, 32);
        sw += __shfl_xor(sw, 32);
        size_t row = rowbase + wid * 8 + qq;
        if (row < (size_t)N && half == 0) {
            vf4 p = { sx, sy, sz, sw };
            __builtin_nontemporal_store(p, (vf4*)(out + row * D + lh * 4));
        }
    }
}

// ---------- Phase 4 fallback (f32): round-0 bucket kernel ----------
__global__ __launch_bounds__(256) void k_bucket2f(const int2* __restrict__ sorted,
                                                  const int* __restrict__ O,
                                                  const int* __restrict__ bs,
                                                  const float2* __restrict__ e2,
                                                  float* __restrict__ out,
                                                  int N, int nb, int E) {
    __shared__ int rowcnt[BROWS], rowoff[BROWS], rowcur[BROWS];
    __shared__ int2 rec2[CAP];
    int b  = blockIdx.x;
    int f0 = b * CHUNKS;
    int beg = O[f0] + bs[f0 >> 10];
    int end;
    if (b + 1 < nb) { int f1 = (b + 1) * CHUNKS; end = O[f1] + bs[f1 >> 10]; }
    else            end = E;
    beg = max(0, min(beg, E));
    end = max(beg, min(end, E));
    int wid = threadIdx.x >> 6, lane = threadIdx.x & 63;

    float2 acc[8];
#pragma unroll
    for (int q = 0; q < 8; ++q) acc[q] = make_float2(0.f, 0.f);

    for (int done = beg; done < end; done += CAP) {
        int cnt = min(CAP, end - done);
        if (threadIdx.x < BROWS) rowcnt[threadIdx.x] = 0;
        __syncthreads();
        for (int k = threadIdx.x; k < cnt; k += 256)
            atomicAdd(&rowcnt[(((unsigned)sorted[done + k].x) >> COLBITS) & (BROWS - 1)], 1);
        __syncthreads();
        if (threadIdx.x < BROWS) {
            int v = rowcnt[threadIdx.x];
            int incl = v;
#pragma unroll
            for (int off = 1; off < BROWS; off <<= 1) {
                int u = __shfl_up(incl, off);
                if ((int)threadIdx.x >= off) incl += u;
            }
            rowoff[threadIdx.x] = incl - v;
            rowcur[threadIdx.x] = incl - v;
        }
        __syncthreads();
        for (int k = threadIdx.x; k < cnt; k += 256) {
            int2 rr = sorted[done + k];
            int row = (((unsigned)rr.x) >> COLBITS) & (BROWS - 1);
            int pos = atomicAdd(&rowcur[row], 1);
            if (pos >= 0 && pos < CAP) rec2[pos] = rr;
        }
        __syncthreads();

#pragma unroll
        for (int q = 0; q < 8; ++q) {
            int row = wid * 8 + q;
            int off = rowoff[row], cr = rowcnt[row];
            int j = 0;
            for (; j + 4 <= cr; j += 4) {
                int2 r0 = rec2[off + j];     int2 r1 = rec2[off + j + 1];
                int2 r2 = rec2[off + j + 2]; int2 r3 = rec2[off + j + 3];
                float v0 = __int_as_float(r0.y), v1 = __int_as_float(r1.y);
                float v2 = __int_as_float(r2.y), v3 = __int_as_float(r3.y);
                float2 g0 = e2[(size_t)(r0.x & COLMASK) * 64 + lane];
                float2 g1 = e2[(size_t)(r1.x & COLMASK) * 64 + lane];
                float2 g2 = e2[(size_t)(r2.x & COLMASK) * 64 + lane];
                float2 g3 = e2[(size_t)(r3.x & COLMASK) * 64 + lane];
                acc[q].x += v0 * g0.x; acc[q].y += v0 * g0.y;
                acc[q].x += v1 * g1.x; acc[q].y += v1 * g1.y;
                acc[q].x += v2 * g2.x; acc[q].y += v2 * g2.y;
                acc[q].x += v3 * g3.x; acc[q].y += v3 * g3.y;
            }
            for (; j < cr; ++j) {
                int2 r0 = rec2[off + j];
                float v0 = __int_as_float(r0.y);
                float2 g0 = e2[(size_t)(r0.x & COLMASK) * 64 + lane];
                acc[q].x += v0 * g0.x;
                acc[q].y += v0 * g0.y;
            }
        }
        __syncthreads();
    }

    size_t rowbase = (size_t)b * BROWS;
    unsigned long long* out64 = (unsigned long long*)out;
#pragma unroll
    for (int q = 0; q < 8; ++q) {
        size_t row = rowbase + wid * 8 + q;
        if (row < (size_t)N) {
            unsigned long long p =
                ((unsigned long long)__float_as_uint(acc[q].y) << 32) |
                (unsigned long long)__float_as_uint(acc[q].x);
            __builtin_nontemporal_store(p, out64 + row * 64 + lane);
        }
    }
}

// ---------- Fallback: direct atomic scatter-add ----------
__global__ void k_atomic(const int* __restrict__ rows, const int* __restrict__ cols,
                         const float* __restrict__ vals, const float2* __restrict__ emb,
                         float* __restrict__ out, int E) {
    long long g = (long long)blockIdx.x * blockDim.x + threadIdx.x;
    int e    = (int)(g >> 6);
    int lane = (int)(g & 63);
    if (e >= E) return;
    int r = rows[e], c = cols[e];
    float v = vals[e];
    float2 em = emb[(size_t)c * (D / 2) + lane];
    atomicAdd(&out[(size_t)r * D + lane * 2    ], v * em.x);
    atomicAdd(&out[(size_t)r * D + lane * 2 + 1], v * em.y);
}

extern "C" void kernel_launch(void* const* d_in, const int* in_sizes, int n_in,
                              void* d_out, int out_size, void* d_ws, size_t ws_size,
                              hipStream_t stream) {
    const int*   adj  = (const int*)d_in[0];
    const float* vals = (const float*)d_in[1];
    const float* emb  = (const float*)d_in[2];
    int E = in_sizes[1];
    int N = in_sizes[2] / D;
    const int* rows = adj;
    const int* cols = adj + E;
    float* out = (float*)d_out;

    int nb   = (N + BROWS - 1) / BROWS;
    int CE   = (E + CHUNKS - 1) / CHUNKS;
    int flat = nb * CHUNKS;
    int nblk = (flat + 1023) / 1024;

    size_t off_sorted = 0;
    size_t sz_sorted  = (size_t)E * 8;
    size_t off_M      = (off_sorted + sz_sorted + 255) & ~(size_t)255;
    size_t sz_M       = (size_t)flat * 4;
    size_t off_O      = (off_M + sz_M + 255) & ~(size_t)255;
    size_t sz_O       = (size_t)flat * 4;
    size_t off_bs     = (off_O + sz_O + 255) & ~(size_t)255;
    size_t sz_bs      = (size_t)nblk * 4;
    size_t off_q      = (off_bs + sz_bs + 255) & ~(size_t)255;
    size_t sz_q       = (size_t)N * 64 * 4;
    size_t need_bf16  = off_q + sz_q;
    size_t need_f32   = off_q;

    bool ok = (N > 0) && (E > 0) && (N <= (1 << COLBITS)) &&
              ((size_t)nb * 4 <= 60000) && (nblk <= 1024);

    if (ok && ws_size >= need_f32) {
        char* ws = (char*)d_ws;
        unsigned long long* sorted = (unsigned long long*)(ws + off_sorted);
        int* M  = (int*)(ws + off_M);
        int* O  = (int*)(ws + off_O);
        int* bs = (int*)(ws + off_bs);
        bool bf16 = (ws_size >= need_bf16);
        unsigned* q = (unsigned*)(ws + off_q);

        int cvtb = bf16 ? CVTB : 0;
        k_prep    <<<CHUNKS + cvtb, PBLK, (size_t)nb * 4, stream>>>(
                      rows, E, CE, nb, M, (const float2*)emb, q, N * 64, cvtb);
        k_scan1   <<<nblk, 1024, 0, stream>>>(M, flat, O, bs);
        k_scan2   <<<1, 1024, 0, stream>>>(bs, nblk);
        k_mscatter<<<CHUNKS, PBLK, (size_t)nb * 4, stream>>>(
                      rows, cols, vals, E, CE, nb, O, bs, sorted);
        if (bf16) {
            k_bucket2b<<<nb, 256, 0, stream>>>((const int2*)sorted, O, bs,
                                               q, out, N, nb, E);
        } else {
            k_bucket2f<<<nb, 256, 0, stream>>>((const int2*)sorted, O, bs,
                                               (const float2*)emb, out, N, nb, E);
        }
    } else {
        hipMemsetAsync(out, 0, (size_t)out_size * sizeof(float), stream);
        long long tot = (long long)E * 64;
        int blocks = (int)((tot + 255) / 256);
        k_atomic<<<blocks, 256, 0, stream>>>(rows, cols, vals, (const float2*)emb, out, E);
    }
}